// Round 1
// baseline (2812.876 us; speedup 1.0000x reference)
//
#include <hip/hip_runtime.h>
#include <hip/hip_bf16.h>
#include <math.h>

// ---- problem constants ----
#define BATCH 16
#define L_SEQ 196            // 14*14 patches
#define PATCH_DIM 768        // 16*16*3
#define D_MODEL 512
#define D_INNER 1024
#define D_STATE 16
#define D_CONV 4
#define DT_RANK 32
#define N_LAYERS 4
#define N_CLASSES 1000
#define ROWS (BATCH * L_SEQ) // 3136

// ---------------------------------------------------------------------------
// posemb: [196,512]  layout [sin(x*w) | cos(x*w) | sin(y*w) | cos(y*w)]
__global__ void posemb_kernel(float* __restrict__ pos) {
    int idx = blockIdx.x * 256 + threadIdx.x;
    if (idx >= L_SEQ * D_MODEL) return;
    int l = idx >> 9, col = idx & 511;
    int q = col >> 7, wi = col & 127;
    float omega = powf(10000.f, -(float)wi / 127.f);
    float yv = (float)(l / 14), xv = (float)(l % 14);
    float arg = (q < 2 ? xv : yv) * omega;
    pos[idx] = (q & 1) ? cosf(arg) : sinf(arg);
}

// patchify: x[B,224,224,3] -> p[3136,768]
__global__ void patchify_kernel(const float* __restrict__ x, float* __restrict__ p) {
    int idx = blockIdx.x * 256 + threadIdx.x;
    if (idx >= ROWS * PATCH_DIM) return;
    int k = idx % PATCH_DIM, row = idx / PATCH_DIM;
    int b = row / L_SEQ, l = row % L_SEQ;
    int i = l / 14, j = l % 14;
    int ph = k / 48, r = k % 48, pw = r / 3, c = r % 3;
    size_t src = (((size_t)b * 224 + i * 16 + ph) * 224 + (j * 16 + pw)) * 3 + c;
    p[idx] = x[src];
}

// ---------------------------------------------------------------------------
// Generic tiled f32 GEMM: C[M,N] (op)= A[M,K] @ W[K,N]
// mode 0: C = acc
// mode 1: C += acc
// mode 2: C = acc + bias[col] + pos[(row%196)*512+col]
// mode 3: C = softplus(acc + bias[col])
// mode 4: C = acc + bias[col]
__global__ __launch_bounds__(256) void gemm_tiled(
    const float* __restrict__ A, int lda,
    const float* __restrict__ W, int ldw,
    float* __restrict__ C, int ldc,
    int M, int N, int K, int mode,
    const float* __restrict__ bias,
    const float* __restrict__ pos)
{
    __shared__ float As[16][65];
    __shared__ float Bs[16][64];
    int bm = blockIdx.y * 64, bn = blockIdx.x * 64;
    int tid = threadIdx.x;
    int tx = tid & 15, ty = tid >> 4;
    float acc[4][4] = {};
    for (int k0 = 0; k0 < K; k0 += 16) {
        int ka = k0 + (tid & 15);
        #pragma unroll
        for (int mi = 0; mi < 4; ++mi) {
            int row = bm + mi * 16 + (tid >> 4);
            As[tid & 15][mi * 16 + (tid >> 4)] =
                (row < M && ka < K) ? A[(size_t)row * lda + ka] : 0.f;
        }
        int cb = bn + (tid & 63);
        #pragma unroll
        for (int ki = 0; ki < 4; ++ki) {
            int k = k0 + ki * 4 + (tid >> 6);
            Bs[ki * 4 + (tid >> 6)][tid & 63] =
                (k < K && cb < N) ? W[(size_t)k * ldw + cb] : 0.f;
        }
        __syncthreads();
        #pragma unroll
        for (int kk = 0; kk < 16; ++kk) {
            float a[4], b[4];
            #pragma unroll
            for (int i = 0; i < 4; ++i) a[i] = As[kk][ty + 16 * i];
            #pragma unroll
            for (int j = 0; j < 4; ++j) b[j] = Bs[kk][tx + 16 * j];
            #pragma unroll
            for (int i = 0; i < 4; ++i)
                #pragma unroll
                for (int j = 0; j < 4; ++j)
                    acc[i][j] += a[i] * b[j];
        }
        __syncthreads();
    }
    #pragma unroll
    for (int i = 0; i < 4; ++i) {
        int row = bm + ty + 16 * i;
        if (row >= M) continue;
        #pragma unroll
        for (int j = 0; j < 4; ++j) {
            int col = bn + tx + 16 * j;
            if (col >= N) continue;
            float v = acc[i][j];
            size_t o = (size_t)row * ldc + col;
            if (mode == 0) C[o] = v;
            else if (mode == 1) C[o] += v;
            else if (mode == 2) C[o] = v + bias[col] + pos[(row % L_SEQ) * D_MODEL + col];
            else if (mode == 3) {
                float z = v + bias[col];
                C[o] = (z > 20.f) ? z : log1pf(__expf(z));
            }
            else C[o] = v + bias[col];
        }
    }
}

// ---------------------------------------------------------------------------
__global__ __launch_bounds__(256) void rmsnorm_kernel(
    const float* __restrict__ h, const float* __restrict__ w, float* __restrict__ o)
{
    int row = blockIdx.x;
    int tid = threadIdx.x;
    const float* hr = h + (size_t)row * D_MODEL;
    float v0 = hr[tid], v1 = hr[tid + 256];
    float ss = v0 * v0 + v1 * v1;
    #pragma unroll
    for (int off = 32; off; off >>= 1) ss += __shfl_down(ss, off);
    __shared__ float ls[4];
    __shared__ float scale_s;
    if ((tid & 63) == 0) ls[tid >> 6] = ss;
    __syncthreads();
    if (tid == 0) {
        float t = ls[0] + ls[1] + ls[2] + ls[3];
        scale_s = rsqrtf(t * (1.f / D_MODEL) + 1e-5f);
    }
    __syncthreads();
    float sc = scale_s;
    o[(size_t)row * D_MODEL + tid] = v0 * sc * w[tid];
    o[(size_t)row * D_MODEL + tid + 256] = v1 * sc * w[tid + 256];
}

// causal depthwise conv (k=4) over sequence + SiLU.  xr: [3136, 2048] (xi = first 1024)
__global__ void conv_silu_kernel(const float* __restrict__ xr,
                                 const float* __restrict__ cw,
                                 float* __restrict__ xs)
{
    int idx = blockIdx.x * 256 + threadIdx.x;
    if (idx >= ROWS * D_INNER) return;
    int d = idx & 1023, row = idx >> 10;
    int l = row % L_SEQ;
    const float* w4 = cw + d * 4;
    float acc = 0.f;
    #pragma unroll
    for (int k = 0; k < 4; ++k) {
        int ls = l - 3 + k;
        if (ls >= 0) acc += xr[(size_t)(row - 3 + k) * (2 * D_INNER) + d] * w4[k];
    }
    xs[idx] = acc / (1.f + __expf(-acc));
}

// selective scan: one block = (batch b, 64-channel chunk); 64 threads, 1 channel each
__global__ __launch_bounds__(64) void scan_kernel(
    const float* __restrict__ xs,     // u      [3136,1024]
    const float* __restrict__ delta,  //        [3136,1024]
    const float* __restrict__ xdbl,   //        [3136,64]  ([32:48]=B, [48:64]=C)
    const float* __restrict__ A_log,  //        [1024,16]  (layer slice)
    const float* __restrict__ Dv,     //        [1024]
    float* __restrict__ y)            //        [3136,1024]
{
    int b = blockIdx.x >> 4;
    int d = ((blockIdx.x & 15) << 6) | threadIdx.x;
    float A[16];
    #pragma unroll
    for (int n = 0; n < 16; ++n) A[n] = -__expf(A_log[d * 16 + n]);
    float Dd = Dv[d];
    float s[16] = {};
    size_t base = (size_t)b * L_SEQ;
    for (int l = 0; l < L_SEQ; ++l) {
        size_t r = base + l;
        float dl = delta[r * D_INNER + d];
        float u  = xs[r * D_INNER + d];
        float du = dl * u;
        const float* bc = xdbl + r * 64;
        float acc = 0.f;
        #pragma unroll
        for (int n = 0; n < 16; ++n) {
            s[n] = __expf(dl * A[n]) * s[n] + du * bc[32 + n];
            acc += s[n] * bc[48 + n];
        }
        y[r * D_INNER + d] = acc + u * Dd;
    }
}

// y *= silu(res)  (res = xr[:, 1024:2048])
__global__ void gate_kernel(float* __restrict__ y, const float* __restrict__ xr) {
    int idx = blockIdx.x * 256 + threadIdx.x;
    if (idx >= ROWS * D_INNER) return;
    int d = idx & 1023, row = idx >> 10;
    float r = xr[(size_t)row * (2 * D_INNER) + D_INNER + d];
    y[idx] *= r / (1.f + __expf(-r));
}

// mean over sequence: h[16,196,512] -> hm[16,512]
__global__ __launch_bounds__(256) void mean_kernel(const float* __restrict__ h,
                                                   float* __restrict__ hm) {
    int b = blockIdx.x, tid = threadIdx.x;
    for (int c = tid; c < D_MODEL; c += 256) {
        float acc = 0.f;
        for (int l = 0; l < L_SEQ; ++l)
            acc += h[((size_t)b * L_SEQ + l) * D_MODEL + c];
        hm[b * D_MODEL + c] = acc * (1.f / L_SEQ);
    }
}

// ---------------------------------------------------------------------------
extern "C" void kernel_launch(void* const* d_in, const int* in_sizes, int n_in,
                              void* d_out, int out_size, void* d_ws, size_t ws_size,
                              hipStream_t stream) {
    const float* x         = (const float*)d_in[0];
    const float* patch_w   = (const float*)d_in[1];
    const float* patch_b   = (const float*)d_in[2];
    const float* norm_w    = (const float*)d_in[3];
    const float* in_proj_w = (const float*)d_in[4];
    const float* conv_w    = (const float*)d_in[5];
    const float* x_proj_w  = (const float*)d_in[6];
    const float* dt_proj_w = (const float*)d_in[7];
    const float* dt_proj_b = (const float*)d_in[8];
    const float* A_log     = (const float*)d_in[9];
    const float* Dv        = (const float*)d_in[10];
    const float* out_proj_w= (const float*)d_in[11];
    const float* head_w    = (const float*)d_in[12];
    const float* head_b    = (const float*)d_in[13];
    float* out = (float*)d_out;

    // workspace layout (floats).  p and xr share region0.
    float* ws = (float*)d_ws;
    size_t off = 0;
    float* region0 = ws + off; off += (size_t)ROWS * (2 * D_INNER);   // 6,422,528 (>= p's 2,408,448)
    float* p    = region0;
    float* xr   = region0;
    float* h    = ws + off; off += (size_t)ROWS * D_MODEL;
    float* xn   = ws + off; off += (size_t)ROWS * D_MODEL;
    float* xs   = ws + off; off += (size_t)ROWS * D_INNER;
    float* xdbl = ws + off; off += (size_t)ROWS * 64;
    float* delta= ws + off; off += (size_t)ROWS * D_INNER;
    float* yb   = ws + off; off += (size_t)ROWS * D_INNER;
    float* hm   = ws + off; off += (size_t)BATCH * D_MODEL;
    float* pos  = ws + off; off += (size_t)L_SEQ * D_MODEL;

    posemb_kernel<<<(L_SEQ * D_MODEL + 255) / 256, 256, 0, stream>>>(pos);
    patchify_kernel<<<(ROWS * PATCH_DIM + 255) / 256, 256, 0, stream>>>(x, p);

    // h = p @ patch_w + patch_b + pos
    gemm_tiled<<<dim3(D_MODEL / 64, ROWS / 64), 256, 0, stream>>>(
        p, PATCH_DIM, patch_w, D_MODEL, h, D_MODEL,
        ROWS, D_MODEL, PATCH_DIM, 2, patch_b, pos);

    for (int layer = 0; layer < N_LAYERS; ++layer) {
        rmsnorm_kernel<<<ROWS, 256, 0, stream>>>(h, norm_w + layer * D_MODEL, xn);

        // xr = xn @ in_proj_w[layer]   [3136,2048]
        gemm_tiled<<<dim3(2 * D_INNER / 64, ROWS / 64), 256, 0, stream>>>(
            xn, D_MODEL, in_proj_w + (size_t)layer * D_MODEL * 2 * D_INNER, 2 * D_INNER,
            xr, 2 * D_INNER, ROWS, 2 * D_INNER, D_MODEL, 0, nullptr, nullptr);

        conv_silu_kernel<<<(ROWS * D_INNER) / 256, 256, 0, stream>>>(
            xr, conv_w + (size_t)layer * D_INNER * D_CONV, xs);

        // xdbl = xs @ x_proj_w[layer]   [3136,64]
        gemm_tiled<<<dim3(1, ROWS / 64), 256, 0, stream>>>(
            xs, D_INNER, x_proj_w + (size_t)layer * D_INNER * 64, 64,
            xdbl, 64, ROWS, 64, D_INNER, 0, nullptr, nullptr);

        // delta = softplus(xdbl[:, :32] @ dt_proj_w[layer] + dt_proj_b[layer])
        gemm_tiled<<<dim3(D_INNER / 64, ROWS / 64), 256, 0, stream>>>(
            xdbl, 64, dt_proj_w + (size_t)layer * DT_RANK * D_INNER, D_INNER,
            delta, D_INNER, ROWS, D_INNER, DT_RANK, 3,
            dt_proj_b + (size_t)layer * D_INNER, nullptr);

        scan_kernel<<<BATCH * (D_INNER / 64), 64, 0, stream>>>(
            xs, delta, xdbl,
            A_log + (size_t)layer * D_INNER * D_STATE,
            Dv + (size_t)layer * D_INNER, yb);

        gate_kernel<<<(ROWS * D_INNER) / 256, 256, 0, stream>>>(yb, xr);

        // h += yb @ out_proj_w[layer]
        gemm_tiled<<<dim3(D_MODEL / 64, ROWS / 64), 256, 0, stream>>>(
            yb, D_INNER, out_proj_w + (size_t)layer * D_INNER * D_MODEL, D_MODEL,
            h, D_MODEL, ROWS, D_MODEL, D_INNER, 1, nullptr, nullptr);
    }

    mean_kernel<<<BATCH, 256, 0, stream>>>(h, hm);

    // out = hm @ head_w + head_b    [16,1000]
    gemm_tiled<<<dim3((N_CLASSES + 63) / 64, 1), 256, 0, stream>>>(
        hm, D_MODEL, head_w, N_CLASSES, out, N_CLASSES,
        BATCH, N_CLASSES, D_MODEL, 4, head_b, nullptr);
}

// Round 2
// 1078.355 us; speedup vs baseline: 2.6085x; 2.6085x over previous
//
#include <hip/hip_runtime.h>
#include <hip/hip_bf16.h>
#include <math.h>

#define BATCH 16
#define L_SEQ 196
#define PATCH_DIM 768
#define D_MODEL 512
#define D_INNER 1024
#define D_STATE 16
#define D_CONV 4
#define DT_RANK 32
#define N_LAYERS 4
#define N_CLASSES 1000
#define ROWS (BATCH * L_SEQ)   // 3136
#define ROWSP 3200             // padded to multiple of 128

typedef __hip_bfloat16 bf16;
typedef __attribute__((ext_vector_type(8))) __bf16 bf16x8;
typedef __attribute__((ext_vector_type(4))) float f32x4;

__device__ __forceinline__ void gload_lds16(const void* g, void* l) {
    __builtin_amdgcn_global_load_lds((const __attribute__((address_space(1))) void*)g,
                                     (__attribute__((address_space(3))) void*)l, 16, 0, 0);
}

// ---------------------------------------------------------------------------
__global__ void posemb_kernel(float* __restrict__ pos) {
    int idx = blockIdx.x * 256 + threadIdx.x;
    if (idx >= L_SEQ * D_MODEL) return;
    int l = idx >> 9, col = idx & 511;
    int q = col >> 7, wi = col & 127;
    float omega = powf(10000.f, -(float)wi / 127.f);
    float yv = (float)(l / 14), xv = (float)(l % 14);
    float arg = (q < 2 ? xv : yv) * omega;
    pos[idx] = (q & 1) ? cosf(arg) : sinf(arg);
}

// patchify: x[B,224,224,3] -> p[3136,768] bf16
__global__ void patchify_kernel(const float* __restrict__ x, bf16* __restrict__ p) {
    int idx = blockIdx.x * 256 + threadIdx.x;
    if (idx >= ROWS * PATCH_DIM) return;
    int k = idx % PATCH_DIM, row = idx / PATCH_DIM;
    int b = row / L_SEQ, l = row % L_SEQ;
    int i = l / 14, j = l % 14;
    int ph = k / 48, r = k % 48, pw = r / 3, c = r % 3;
    size_t src = (((size_t)b * 224 + i * 16 + ph) * 224 + (j * 16 + pw)) * 3 + c;
    p[idx] = __float2bfloat16(x[src]);
}

// transpose-convert: src[K][N] f32 -> dst[Npad][K] bf16 (zero-fill n>=N), per-layer z
__global__ __launch_bounds__(256) void transpose_bf16_kernel(
    const float* __restrict__ src, bf16* __restrict__ dst,
    int K, int N, int Npad, size_t src_lstride, size_t dst_lstride)
{
    src += (size_t)blockIdx.z * src_lstride;
    dst += (size_t)blockIdx.z * dst_lstride;
    __shared__ float tile[32][33];
    int kb = blockIdx.y * 32, nb = blockIdx.x * 32;
    int tx = threadIdx.x & 31, ty = threadIdx.x >> 5;  // 32 x 8
    #pragma unroll
    for (int i = 0; i < 4; ++i) {
        int k = kb + ty + 8 * i, n = nb + tx;
        tile[ty + 8 * i][tx] = (k < K && n < N) ? src[(size_t)k * N + n] : 0.f;
    }
    __syncthreads();
    #pragma unroll
    for (int i = 0; i < 4; ++i) {
        int n = nb + ty + 8 * i, k = kb + tx;
        if (n < Npad && k < K) dst[(size_t)n * K + k] = __float2bfloat16(tile[tx][ty + 8 * i]);
    }
}

// ---------------------------------------------------------------------------
// bf16 MFMA GEMM, m97-structure: BM=BN=128, BK=32, 4 waves (2x2), 16x16x32 MFMA.
// A [Mpad][K] bf16 row-major; Wt [Npad][K] bf16 row-major (= W^T).
// LDS chunk swizzle: chunk (row, kb) stored at (row, kb ^ ((row>>1)&3)); staging
// fetches the inverse-permuted global chunk so LDS writes stay linear.
// MODE 0: Cb = bf16(acc)
// MODE 1: Cf = acc
// MODE 2: Cf = acc + bias[col] + pos[(row%196)*512+col]
// MODE 3: Cf += acc
template<int MODE>
__global__ __launch_bounds__(256) void gemm_mfma(
    const bf16* __restrict__ A, const bf16* __restrict__ Wt,
    int K, int Nstore, int M, int ldc,
    float* __restrict__ Cf, bf16* __restrict__ Cb,
    const float* __restrict__ bias, const float* __restrict__ pos)
{
    __shared__ short Als[128 * 32];
    __shared__ short Bls[128 * 32];
    int tid = threadIdx.x;
    int lane = tid & 63, wid = tid >> 6;
    int wm = wid >> 1, wn = wid & 1;
    int bm = blockIdx.y * 128, bn = blockIdx.x * 128;

    f32x4 acc[4][4];
    #pragma unroll
    for (int i = 0; i < 4; ++i)
        #pragma unroll
        for (int j = 0; j < 4; ++j)
            acc[i][j] = (f32x4){0.f, 0.f, 0.f, 0.f};

    for (int k0 = 0; k0 < K; k0 += 32) {
        // stage A and B tiles: 512 chunks of 16B each, 2 issues/wave/matrix
        #pragma unroll
        for (int i = 0; i < 2; ++i) {
            int cbase = (i * 4 + wid) * 64;
            int c = cbase + lane;
            int row = c >> 2, kbp = c & 3;
            int kb = kbp ^ ((row >> 1) & 3);
            gload_lds16(A + (size_t)(bm + row) * K + k0 + kb * 8, Als + (size_t)cbase * 8);
            gload_lds16(Wt + (size_t)(bn + row) * K + k0 + kb * 8, Bls + (size_t)cbase * 8);
        }
        __syncthreads();
        bf16x8 af[4], bfr[4];
        #pragma unroll
        for (int mi = 0; mi < 4; ++mi) {
            int row = wm * 64 + mi * 16 + (lane & 15);
            int kbp = (lane >> 4) ^ ((row >> 1) & 3);
            af[mi] = *reinterpret_cast<const bf16x8*>(Als + row * 32 + kbp * 8);
        }
        #pragma unroll
        for (int nj = 0; nj < 4; ++nj) {
            int row = wn * 64 + nj * 16 + (lane & 15);
            int kbp = (lane >> 4) ^ ((row >> 1) & 3);
            bfr[nj] = *reinterpret_cast<const bf16x8*>(Bls + row * 32 + kbp * 8);
        }
        #pragma unroll
        for (int mi = 0; mi < 4; ++mi)
            #pragma unroll
            for (int nj = 0; nj < 4; ++nj)
                acc[mi][nj] = __builtin_amdgcn_mfma_f32_16x16x32_bf16(af[mi], bfr[nj], acc[mi][nj], 0, 0, 0);
        __syncthreads();
    }

    // epilogue: C[row][col], col=lane&15, row=(lane>>4)*4+j within each 16x16 frag
    #pragma unroll
    for (int mi = 0; mi < 4; ++mi) {
        #pragma unroll
        for (int nj = 0; nj < 4; ++nj) {
            int r0 = bm + wm * 64 + mi * 16 + ((lane >> 4) << 2);
            int col = bn + wn * 64 + nj * 16 + (lane & 15);
            if (col >= Nstore) continue;
            #pragma unroll
            for (int j = 0; j < 4; ++j) {
                int row = r0 + j;
                if (row >= M) continue;
                float v = acc[mi][nj][j];
                size_t o = (size_t)row * ldc + col;
                if (MODE == 0) Cb[o] = __float2bfloat16(v);
                else if (MODE == 1) Cf[o] = v;
                else if (MODE == 2) Cf[o] = v + bias[col] + pos[(size_t)(row % L_SEQ) * D_MODEL + col];
                else Cf[o] += v;
            }
        }
    }
}

// ---------------------------------------------------------------------------
// f32 tiled GEMM (kept for dt_proj K=32 and head M=16)
// mode 3: C = softplus(acc + bias[col]);  mode 4: C = acc + bias[col]
__global__ __launch_bounds__(256) void gemm_tiled(
    const float* __restrict__ A, int lda,
    const float* __restrict__ W, int ldw,
    float* __restrict__ C, int ldc,
    int M, int N, int K, int mode,
    const float* __restrict__ bias)
{
    __shared__ float As[16][65];
    __shared__ float Bs[16][64];
    int bm = blockIdx.y * 64, bn = blockIdx.x * 64;
    int tid = threadIdx.x;
    int tx = tid & 15, ty = tid >> 4;
    float acc[4][4] = {};
    for (int k0 = 0; k0 < K; k0 += 16) {
        int ka = k0 + (tid & 15);
        #pragma unroll
        for (int mi = 0; mi < 4; ++mi) {
            int row = bm + mi * 16 + (tid >> 4);
            As[tid & 15][mi * 16 + (tid >> 4)] =
                (row < M && ka < K) ? A[(size_t)row * lda + ka] : 0.f;
        }
        int cb = bn + (tid & 63);
        #pragma unroll
        for (int ki = 0; ki < 4; ++ki) {
            int k = k0 + ki * 4 + (tid >> 6);
            Bs[ki * 4 + (tid >> 6)][tid & 63] =
                (k < K && cb < N) ? W[(size_t)k * ldw + cb] : 0.f;
        }
        __syncthreads();
        #pragma unroll
        for (int kk = 0; kk < 16; ++kk) {
            float a[4], b[4];
            #pragma unroll
            for (int i = 0; i < 4; ++i) a[i] = As[kk][ty + 16 * i];
            #pragma unroll
            for (int j = 0; j < 4; ++j) b[j] = Bs[kk][tx + 16 * j];
            #pragma unroll
            for (int i = 0; i < 4; ++i)
                #pragma unroll
                for (int j = 0; j < 4; ++j)
                    acc[i][j] += a[i] * b[j];
        }
        __syncthreads();
    }
    #pragma unroll
    for (int i = 0; i < 4; ++i) {
        int row = bm + ty + 16 * i;
        if (row >= M) continue;
        #pragma unroll
        for (int j = 0; j < 4; ++j) {
            int col = bn + tx + 16 * j;
            if (col >= N) continue;
            float v = acc[i][j];
            size_t o = (size_t)row * ldc + col;
            if (mode == 3) {
                float z = v + bias[col];
                C[o] = (z > 20.f) ? z : log1pf(__expf(z));
            } else {
                C[o] = v + bias[col];
            }
        }
    }
}

// ---------------------------------------------------------------------------
__global__ __launch_bounds__(256) void rmsnorm_kernel(
    const float* __restrict__ h, const float* __restrict__ w, bf16* __restrict__ o)
{
    int row = blockIdx.x;
    int tid = threadIdx.x;
    const float* hr = h + (size_t)row * D_MODEL;
    float v0 = hr[tid], v1 = hr[tid + 256];
    float ss = v0 * v0 + v1 * v1;
    #pragma unroll
    for (int off = 32; off; off >>= 1) ss += __shfl_down(ss, off);
    __shared__ float ls[4];
    __shared__ float scale_s;
    if ((tid & 63) == 0) ls[tid >> 6] = ss;
    __syncthreads();
    if (tid == 0) {
        float t = ls[0] + ls[1] + ls[2] + ls[3];
        scale_s = rsqrtf(t * (1.f / D_MODEL) + 1e-5f);
    }
    __syncthreads();
    float sc = scale_s;
    o[(size_t)row * D_MODEL + tid]       = __float2bfloat16(v0 * sc * w[tid]);
    o[(size_t)row * D_MODEL + tid + 256] = __float2bfloat16(v1 * sc * w[tid + 256]);
}

// causal depthwise conv (k=4) + SiLU.  xr: [3136,2048] bf16 (xi = first 1024)
__global__ void conv_silu_kernel(const bf16* __restrict__ xr,
                                 const float* __restrict__ cw,
                                 bf16* __restrict__ xs)
{
    int idx = blockIdx.x * 256 + threadIdx.x;
    if (idx >= ROWS * D_INNER) return;
    int d = idx & 1023, row = idx >> 10;
    int l = row % L_SEQ;
    const float* w4 = cw + d * 4;
    float acc = 0.f;
    #pragma unroll
    for (int k = 0; k < 4; ++k) {
        int ls = l - 3 + k;
        if (ls >= 0) acc += __bfloat162float(xr[(size_t)(row - 3 + k) * (2 * D_INNER) + d]) * w4[k];
    }
    float v = acc / (1.f + __expf(-acc));
    xs[idx] = __float2bfloat16(v);
}

// selective scan + fused output gate.  one thread per (b, channel)
__global__ __launch_bounds__(64) void scan_kernel(
    const bf16*  __restrict__ xs,     // u    [3136,1024] bf16
    const float* __restrict__ delta,  //      [3136,1024] f32
    const float* __restrict__ xdbl,   //      [3136,64]   ([32:48]=B, [48:64]=C)
    const float* __restrict__ A_log,  //      [1024,16]
    const float* __restrict__ Dv,     //      [1024]
    const bf16*  __restrict__ xr,     // res  [3136,2048] (cols 1024..2047)
    bf16* __restrict__ y)             //      [3136,1024] bf16
{
    int b = blockIdx.x >> 4;
    int d = ((blockIdx.x & 15) << 6) | threadIdx.x;
    float A[16];
    #pragma unroll
    for (int n = 0; n < 16; ++n) A[n] = -__expf(A_log[d * 16 + n]);
    float Dd = Dv[d];
    float s[16] = {};
    size_t base = (size_t)b * L_SEQ;
    for (int l = 0; l < L_SEQ; ++l) {
        size_t r = base + l;
        float dl = delta[r * D_INNER + d];
        float u  = __bfloat162float(xs[r * D_INNER + d]);
        float du = dl * u;
        const float* bc = xdbl + r * 64;
        float acc = 0.f;
        #pragma unroll
        for (int n = 0; n < 16; ++n) {
            s[n] = __expf(dl * A[n]) * s[n] + du * bc[32 + n];
            acc += s[n] * bc[48 + n];
        }
        float res = __bfloat162float(xr[r * (2 * D_INNER) + D_INNER + d]);
        float g = res / (1.f + __expf(-res));
        y[r * D_INNER + d] = __float2bfloat16((acc + u * Dd) * g);
    }
}

// mean over sequence: h[16,196,512] f32 -> hm[16,512] f32
__global__ __launch_bounds__(256) void mean_kernel(const float* __restrict__ h,
                                                   float* __restrict__ hm) {
    int b = blockIdx.x, tid = threadIdx.x;
    for (int c = tid; c < D_MODEL; c += 256) {
        float acc = 0.f;
        for (int l = 0; l < L_SEQ; ++l)
            acc += h[((size_t)b * L_SEQ + l) * D_MODEL + c];
        hm[b * D_MODEL + c] = acc * (1.f / L_SEQ);
    }
}

// ---------------------------------------------------------------------------
extern "C" void kernel_launch(void* const* d_in, const int* in_sizes, int n_in,
                              void* d_out, int out_size, void* d_ws, size_t ws_size,
                              hipStream_t stream) {
    const float* x         = (const float*)d_in[0];
    const float* patch_w   = (const float*)d_in[1];
    const float* patch_b   = (const float*)d_in[2];
    const float* norm_w    = (const float*)d_in[3];
    const float* in_proj_w = (const float*)d_in[4];
    const float* conv_w    = (const float*)d_in[5];
    const float* x_proj_w  = (const float*)d_in[6];
    const float* dt_proj_w = (const float*)d_in[7];
    const float* dt_proj_b = (const float*)d_in[8];
    const float* A_log     = (const float*)d_in[9];
    const float* Dv        = (const float*)d_in[10];
    const float* out_proj_w= (const float*)d_in[11];
    const float* head_w    = (const float*)d_in[12];
    const float* head_b    = (const float*)d_in[13];
    float* out = (float*)d_out;

    // byte-based workspace allocator (256B aligned regions)
    char* base = (char*)d_ws;
    size_t off = 0;
    auto alloc = [&](size_t bytes) -> void* {
        void* p = base + off;
        off += (bytes + 255) & ~(size_t)255;
        return p;
    };
    float* pos   = (float*)alloc((size_t)L_SEQ * D_MODEL * 4);
    bf16*  p     = (bf16*) alloc((size_t)ROWSP * PATCH_DIM * 2);
    bf16*  pwT   = (bf16*) alloc((size_t)D_MODEL * PATCH_DIM * 2);
    bf16*  inT   = (bf16*) alloc((size_t)N_LAYERS * 2 * D_INNER * D_MODEL * 2);
    bf16*  xpT   = (bf16*) alloc((size_t)N_LAYERS * 128 * D_INNER * 2);
    bf16*  opT   = (bf16*) alloc((size_t)N_LAYERS * D_MODEL * D_INNER * 2);
    float* h     = (float*)alloc((size_t)ROWS * D_MODEL * 4);
    bf16*  xn    = (bf16*) alloc((size_t)ROWSP * D_MODEL * 2);
    bf16*  xr    = (bf16*) alloc((size_t)ROWSP * 2 * D_INNER * 2);
    bf16*  xs    = (bf16*) alloc((size_t)ROWSP * D_INNER * 2);
    float* xdbl  = (float*)alloc((size_t)ROWSP * 64 * 4);
    float* delta = (float*)alloc((size_t)ROWS * D_INNER * 4);
    bf16*  yb    = (bf16*) alloc((size_t)ROWSP * D_INNER * 2);
    float* hm    = (float*)alloc((size_t)BATCH * D_MODEL * 4);

    posemb_kernel<<<(L_SEQ * D_MODEL + 255) / 256, 256, 0, stream>>>(pos);
    patchify_kernel<<<(ROWS * PATCH_DIM + 255) / 256, 256, 0, stream>>>(x, p);

    // weight prep: f32 [K][N] -> bf16 [Npad][K]
    transpose_bf16_kernel<<<dim3(16, 24, 1), 256, 0, stream>>>(
        patch_w, pwT, PATCH_DIM, D_MODEL, D_MODEL, 0, 0);
    transpose_bf16_kernel<<<dim3(64, 16, N_LAYERS), 256, 0, stream>>>(
        in_proj_w, inT, D_MODEL, 2 * D_INNER, 2 * D_INNER,
        (size_t)D_MODEL * 2 * D_INNER, (size_t)2 * D_INNER * D_MODEL);
    transpose_bf16_kernel<<<dim3(4, 32, N_LAYERS), 256, 0, stream>>>(
        x_proj_w, xpT, D_INNER, 64, 128,
        (size_t)D_INNER * 64, (size_t)128 * D_INNER);
    transpose_bf16_kernel<<<dim3(16, 32, N_LAYERS), 256, 0, stream>>>(
        out_proj_w, opT, D_INNER, D_MODEL, D_MODEL,
        (size_t)D_INNER * D_MODEL, (size_t)D_MODEL * D_INNER);

    // h = p @ patch_w + patch_b + pos
    gemm_mfma<2><<<dim3(D_MODEL / 128, ROWSP / 128), 256, 0, stream>>>(
        p, pwT, PATCH_DIM, D_MODEL, ROWS, D_MODEL, h, nullptr, patch_b, pos);

    for (int layer = 0; layer < N_LAYERS; ++layer) {
        rmsnorm_kernel<<<ROWS, 256, 0, stream>>>(h, norm_w + layer * D_MODEL, xn);

        // xr = xn @ in_proj  [3136,2048] bf16
        gemm_mfma<0><<<dim3(2 * D_INNER / 128, ROWSP / 128), 256, 0, stream>>>(
            xn, inT + (size_t)layer * 2 * D_INNER * D_MODEL,
            D_MODEL, 2 * D_INNER, ROWS, 2 * D_INNER, nullptr, xr, nullptr, nullptr);

        conv_silu_kernel<<<(ROWS * D_INNER) / 256, 256, 0, stream>>>(
            xr, conv_w + (size_t)layer * D_INNER * D_CONV, xs);

        // xdbl = xs @ x_proj  [3136,64] f32 (N padded to 128, stores guarded)
        gemm_mfma<1><<<dim3(1, ROWSP / 128), 256, 0, stream>>>(
            xs, xpT + (size_t)layer * 128 * D_INNER,
            D_INNER, 64, ROWS, 64, xdbl, nullptr, nullptr, nullptr);

        // delta = softplus(xdbl[:, :32] @ dt_proj_w + dt_proj_b)  f32
        gemm_tiled<<<dim3(D_INNER / 64, (ROWS + 63) / 64), 256, 0, stream>>>(
            xdbl, 64, dt_proj_w + (size_t)layer * DT_RANK * D_INNER, D_INNER,
            delta, D_INNER, ROWS, D_INNER, DT_RANK, 3,
            dt_proj_b + (size_t)layer * D_INNER);

        // selective scan + fused gate -> yb bf16
        scan_kernel<<<BATCH * (D_INNER / 64), 64, 0, stream>>>(
            xs, delta, xdbl,
            A_log + (size_t)layer * D_INNER * D_STATE,
            Dv + (size_t)layer * D_INNER, xr, yb);

        // h += yb @ out_proj
        gemm_mfma<3><<<dim3(D_MODEL / 128, ROWSP / 128), 256, 0, stream>>>(
            yb, opT + (size_t)layer * D_MODEL * D_INNER,
            D_INNER, D_MODEL, ROWS, D_MODEL, h, nullptr, nullptr, nullptr);
    }

    mean_kernel<<<BATCH, 256, 0, stream>>>(h, hm);

    // out = hm @ head_w + head_b   [16,1000]
    gemm_tiled<<<dim3((N_CLASSES + 63) / 64, 1), 256, 0, stream>>>(
        hm, D_MODEL, head_w, N_CLASSES, out, N_CLASSES,
        BATCH, N_CLASSES, D_MODEL, 4, head_b);
}